// Round 1
// baseline (1064.300 us; speedup 1.0000x reference)
//
#include <hip/hip_runtime.h>
#include <hip/hip_bf16.h>
#include <stdint.h>

typedef __attribute__((ext_vector_type(8))) short bf16x8;
typedef __attribute__((ext_vector_type(4))) float f32x4;
typedef __attribute__((ext_vector_type(4))) unsigned short us4;

#define T_TOK 8192
#define DDIM 1024
#define FDIM 4096
#define F2DIM 2048
#define NEXP 8

__device__ __forceinline__ unsigned short f2bf(float f) {
    unsigned u = __float_as_uint(f);
    u += 0x7fffu + ((u >> 16) & 1u);
    return (unsigned short)(u >> 16);
}
__device__ __forceinline__ float bf2f(unsigned short h) {
    return __uint_as_float(((unsigned)h) << 16);
}

// async global->LDS, 16B per lane. LDS dest is wave-uniform base + lane*16.
__device__ __forceinline__ void gl2lds16(const void* g, void* l) {
    __builtin_amdgcn_global_load_lds(
        (const __attribute__((address_space(1))) unsigned int*)(unsigned long long)g,
        (__attribute__((address_space(3))) unsigned int*)(unsigned int)(unsigned long long)l,
        16, 0, 0);
}

// ---------------- router: logits -> softmax top2 (renormalized) ----------------
__global__ void k_router(const float* __restrict__ x, const float* __restrict__ rw,
                         const float* __restrict__ rb, int* __restrict__ eid,
                         float* __restrict__ ewt, int* __restrict__ cnt) {
    const int wid = threadIdx.x >> 6, lane = threadIdx.x & 63;
    const int t = blockIdx.x * 4 + wid;
    float acc[8];
#pragma unroll
    for (int e = 0; e < 8; ++e) acc[e] = 0.f;
    const float4* xr = (const float4*)(x + (long long)t * DDIM);
#pragma unroll
    for (int c = 0; c < 4; ++c) {
        float4 xv = xr[lane + 64 * c];
        int d0 = (lane + 64 * c) * 4;
        float xs[4] = {xv.x, xv.y, xv.z, xv.w};
#pragma unroll
        for (int j = 0; j < 4; ++j) {
            const float* wrow = rw + (long long)(d0 + j) * 8;
#pragma unroll
            for (int e = 0; e < 8; ++e) acc[e] += xs[j] * wrow[e];
        }
    }
#pragma unroll
    for (int off = 32; off; off >>= 1)
#pragma unroll
        for (int e = 0; e < 8; ++e) acc[e] += __shfl_xor(acc[e], off);
    if (lane == 0) {
        float lg[8];
#pragma unroll
        for (int e = 0; e < 8; ++e) lg[e] = acc[e] + rb[e];
        int e0 = 0;
#pragma unroll
        for (int e = 1; e < 8; ++e) if (lg[e] > lg[e0]) e0 = e;
        int e1 = -1;
#pragma unroll
        for (int e = 0; e < 8; ++e) {
            if (e == e0) continue;
            if (e1 < 0 || lg[e] > lg[e1]) e1 = e;
        }
        // renormalized top-2 of softmax == softmax over the two logits
        float w0 = 1.f / (1.f + expf(lg[e1] - lg[e0]));
        eid[2 * t] = e0; eid[2 * t + 1] = e1;
        ewt[2 * t] = w0; ewt[2 * t + 1] = 1.f - w0;
        atomicAdd(&cnt[e0], 1);
        atomicAdd(&cnt[e1], 1);
    }
}

__global__ void k_scan(const int* __restrict__ cnt, int* __restrict__ offs,
                       int* __restrict__ cursor) {
    if (threadIdx.x == 0) {
        int s = 0;
        for (int e = 0; e < NEXP; ++e) { offs[e] = s; cursor[e] = s; s += cnt[e]; }
        offs[NEXP] = s;
    }
}

__global__ void k_scatter(const int* __restrict__ eid, const float* __restrict__ ewt,
                          int* __restrict__ cursor, int* __restrict__ rowtok,
                          float* __restrict__ roww) {
    int t = blockIdx.x * blockDim.x + threadIdx.x;
#pragma unroll
    for (int k = 0; k < 2; ++k) {
        int e = eid[2 * t + k];
        int p = atomicAdd(&cursor[e], 1);
        rowtok[p] = (t << 1) | k;
        roww[p] = ewt[2 * t + k];
    }
}

// ---------------- f32 -> bf16 convert (same layout) ----------------
__global__ void k_cvt(const float* __restrict__ in, unsigned short* __restrict__ out,
                      long long n4) {
    long long i = (long long)blockIdx.x * blockDim.x + threadIdx.x;
    long long stride = (long long)gridDim.x * blockDim.x;
    for (; i < n4; i += stride) {
        float4 v = ((const float4*)in)[i];
        us4 o;
        o.x = f2bf(v.x); o.y = f2bf(v.y); o.z = f2bf(v.z); o.w = f2bf(v.w);
        ((us4*)out)[i] = o;
    }
}

// ---------------- transpose + convert: in [R][C] f32 -> out [C][R] bf16 --------
__global__ void k_tp(const float* __restrict__ in, unsigned short* __restrict__ out,
                     int R, int C) {
    long long base = (long long)blockIdx.z * R * C;
    __shared__ float tile[32][33];
    const int tx = threadIdx.x & 31, ty = threadIdx.x >> 5;
    const int c0 = blockIdx.x * 32, r0 = blockIdx.y * 32;
#pragma unroll
    for (int i = 0; i < 4; ++i) {
        int r = r0 + ty + i * 8;
        tile[ty + i * 8][tx] = in[base + (long long)r * C + c0 + tx];
    }
    __syncthreads();
#pragma unroll
    for (int i = 0; i < 4; ++i) {
        int c = c0 + ty + i * 8;
        out[base + (long long)c * R + r0 + tx] = f2bf(tile[tx][ty + i * 8]);
    }
}

// ---------------- grouped GEMM, m97 structure ----------------
// C[M,N] = A[M,K] @ Bt[N,K]^T ; 128x128 tile, BK=32, 4 waves, 16x16x32 bf16 MFMA.
// MODE 0: A=xb gathered via rowtok, epilogue gelu((acc+b1)*gate) -> hbuf bf16
// MODE 1: A=hbuf (compact rows), epilogue (acc+b2)*roww, scatter -> ybuf[slot][tok]
// MODE 2: A=xb direct, epilogue gelu((acc+sb1)*sgate) -> hs bf16
// MODE 3: A=hs direct, epilogue (acc+sb2)*sigmoid(sw) -> ysh bf16
template <int MODE>
__launch_bounds__(256, 2)
__global__ void k_gemm(const short* __restrict__ A, const short* __restrict__ Bt,
                       const float* __restrict__ bias, const float* __restrict__ gatev,
                       unsigned short* __restrict__ outb, const int* __restrict__ cnt,
                       const int* __restrict__ offs, const int* __restrict__ rowtok,
                       const float* __restrict__ roww, const float* __restrict__ swp,
                       int Kd, int Ncols, long long btStride, int biasStride) {
    const int e = blockIdx.z;
    int M, oE;
    if (MODE == 0 || MODE == 1) { M = cnt[e]; oE = offs[e]; }
    else { M = T_TOK; oE = 0; }
    const int tm = blockIdx.y, tn = blockIdx.x;
    if (tm * 128 >= M) return;

    __shared__ short As[128][32];
    __shared__ short Bs[128][32];

    const int tid = threadIdx.x, w = tid >> 6, lane = tid & 63;

    // per-thread global src pointers for the 4 staged 16B chunks (2 A + 2 B)
    const short* ag[2];
#pragma unroll
    for (int c = 0; c < 2; ++c) {
        int id = tid + c * 256;
        int r = tm * 128 + (id >> 2);
        if (r > M - 1) r = M - 1;
        long long rowix;
        if (MODE == 0)      rowix = (long long)(rowtok[oE + r] >> 1);
        else if (MODE == 1) rowix = (long long)(oE + r);
        else                rowix = (long long)r;
        ag[c] = A + rowix * (long long)Kd + (long long)((id & 3) * 8);
    }
    const short* bg[2];
#pragma unroll
    for (int c = 0; c < 2; ++c) {
        int id = tid + c * 256;
        int n = tn * 128 + (id >> 2);
        bg[c] = Bt + (long long)e * btStride + (long long)n * Kd + (long long)((id & 3) * 8);
    }
    // wave-uniform LDS dest bases (HW adds lane*16)
    short* asb[2] = { &As[0][0] + (0 * 256 + w * 64) * 8, &As[0][0] + (256 + w * 64) * 8 };
    short* bsb[2] = { &Bs[0][0] + (0 * 256 + w * 64) * 8, &Bs[0][0] + (256 + w * 64) * 8 };

    const int fr = lane & 15, fg = lane >> 4;
    const int wr = w >> 1, wc = w & 1;

    f32x4 acc[4][4];
#pragma unroll
    for (int m = 0; m < 4; ++m)
#pragma unroll
        for (int n = 0; n < 4; ++n)
            acc[m][n] = (f32x4){0.f, 0.f, 0.f, 0.f};

    const int nk = Kd / 32;
    for (int kt = 0; kt < nk; ++kt) {
        gl2lds16(ag[0], asb[0]); gl2lds16(ag[1], asb[1]);
        gl2lds16(bg[0], bsb[0]); gl2lds16(bg[1], bsb[1]);
        ag[0] += 32; ag[1] += 32; bg[0] += 32; bg[1] += 32;
        __syncthreads();   // drains vmcnt (global_load_lds) + lgkm before barrier

        bf16x8 a[4], b[4];
#pragma unroll
        for (int m = 0; m < 4; ++m)
            a[m] = *(const bf16x8*)(&As[wr * 64 + m * 16 + fr][fg * 8]);
#pragma unroll
        for (int n = 0; n < 4; ++n)
            b[n] = *(const bf16x8*)(&Bs[wc * 64 + n * 16 + fr][fg * 8]);
#pragma unroll
        for (int m = 0; m < 4; ++m)
#pragma unroll
            for (int n = 0; n < 4; ++n)
                acc[m][n] = __builtin_amdgcn_mfma_f32_16x16x32_bf16(a[m], b[n], acc[m][n], 0, 0, 0);
        __syncthreads();   // all waves done reading LDS before next stage
    }

    // epilogue. C/D layout: col=lane&15, row=(lane>>4)*4+i  [m89-verified]
    const int mrow0 = tm * 128 + wr * 64;
    const int col0 = tn * 128 + wc * 64;
    const int biasOff = e * biasStride;

    if (MODE == 0 || MODE == 2) {
#pragma unroll
        for (int n = 0; n < 4; ++n) {
            int col = col0 + n * 16 + fr;
            float bv = bias[biasOff + col];
            float gv = gatev[biasOff + col];
#pragma unroll
            for (int m = 0; m < 4; ++m) {
#pragma unroll
                for (int i = 0; i < 4; ++i) {
                    int grow = mrow0 + m * 16 + fg * 4 + i;
                    if (grow < M) {
                        float v = (acc[m][n][i] + bv) * gv;
                        float h = 0.5f * v * (1.0f + erff(v * 0.70710678118654752f));
                        outb[(long long)(oE + grow) * Ncols + col] = f2bf(h);
                    }
                }
            }
        }
    } else if (MODE == 1) {
#pragma unroll
        for (int n = 0; n < 4; ++n) {
            int col = col0 + n * 16 + fr;
            float bv = bias[biasOff + col];
#pragma unroll
            for (int m = 0; m < 4; ++m) {
#pragma unroll
                for (int i = 0; i < 4; ++i) {
                    int grow = mrow0 + m * 16 + fg * 4 + i;
                    if (grow < M) {
                        int ent = rowtok[oE + grow];
                        float wv = roww[oE + grow];
                        int tok = ent >> 1, slot = ent & 1;
                        float v = (acc[m][n][i] + bv) * wv;
                        outb[((long long)slot * T_TOK + tok) * DDIM + col] = f2bf(v);
                    }
                }
            }
        }
    } else {  // MODE 3
        float sigw = 1.f / (1.f + expf(-swp[0]));
#pragma unroll
        for (int n = 0; n < 4; ++n) {
            int col = col0 + n * 16 + fr;
            float bv = bias[col];
#pragma unroll
            for (int m = 0; m < 4; ++m) {
#pragma unroll
                for (int i = 0; i < 4; ++i) {
                    int grow = mrow0 + m * 16 + fg * 4 + i;
                    if (grow < M) {
                        float v = (acc[m][n][i] + bv) * sigw;
                        outb[(long long)grow * Ncols + col] = f2bf(v);
                    }
                }
            }
        }
    }
}

// ---------------- final: y = y0+y1+ysh ; LayerNorm over D ----------------
__global__ void k_ln(const unsigned short* __restrict__ y0,
                     const unsigned short* __restrict__ y1,
                     const unsigned short* __restrict__ ysh,
                     const float* __restrict__ g, const float* __restrict__ b,
                     float* __restrict__ out) {
    const int wid = threadIdx.x >> 6, lane = threadIdx.x & 63;
    const long long t = (long long)blockIdx.x * 4 + wid;
    const long long base = t * DDIM;
    float v[16];
    float s = 0.f, sq = 0.f;
#pragma unroll
    for (int j = 0; j < 2; ++j) {
        int c0 = (lane + 64 * j) * 8;
        uint4 a0 = *(const uint4*)(y0 + base + c0);
        uint4 a1 = *(const uint4*)(y1 + base + c0);
        uint4 a2 = *(const uint4*)(ysh + base + c0);
        const unsigned* u0 = (const unsigned*)&a0;
        const unsigned* u1 = (const unsigned*)&a1;
        const unsigned* u2 = (const unsigned*)&a2;
#pragma unroll
        for (int q = 0; q < 4; ++q) {
            float lo = bf2f((unsigned short)u0[q]) + bf2f((unsigned short)u1[q]) +
                       bf2f((unsigned short)u2[q]);
            float hi = bf2f((unsigned short)(u0[q] >> 16)) + bf2f((unsigned short)(u1[q] >> 16)) +
                       bf2f((unsigned short)(u2[q] >> 16));
            v[j * 8 + q * 2] = lo;
            v[j * 8 + q * 2 + 1] = hi;
            s += lo + hi;
            sq += lo * lo + hi * hi;
        }
    }
#pragma unroll
    for (int off = 32; off; off >>= 1) {
        s += __shfl_xor(s, off);
        sq += __shfl_xor(sq, off);
    }
    const float mean = s * (1.f / DDIM);
    const float var = sq * (1.f / DDIM) - mean * mean;
    const float inv = rsqrtf(var + 1e-5f);
#pragma unroll
    for (int j = 0; j < 2; ++j) {
        int c0 = (lane + 64 * j) * 8;
#pragma unroll
        for (int h = 0; h < 2; ++h) {
            float4 o4;
            float* op = (float*)&o4;
#pragma unroll
            for (int q = 0; q < 4; ++q) {
                int k = h * 4 + q;
                int col = c0 + k;
                op[q] = (v[j * 8 + k] - mean) * inv * g[col] + b[col];
            }
            *(float4*)(out + base + c0 + h * 4) = o4;
        }
    }
}

extern "C" void kernel_launch(void* const* d_in, const int* in_sizes, int n_in,
                              void* d_out, int out_size, void* d_ws, size_t ws_size,
                              hipStream_t stream) {
    const float* x    = (const float*)d_in[0];
    const float* rw   = (const float*)d_in[1];
    const float* rb   = (const float*)d_in[2];
    const float* w1   = (const float*)d_in[3];
    const float* b1   = (const float*)d_in[4];
    const float* gate = (const float*)d_in[5];
    const float* w2   = (const float*)d_in[6];
    const float* b2   = (const float*)d_in[7];
    const float* sw1  = (const float*)d_in[8];
    const float* sb1  = (const float*)d_in[9];
    const float* sgate= (const float*)d_in[10];
    const float* sw2  = (const float*)d_in[11];
    const float* sb2  = (const float*)d_in[12];
    const float* swt  = (const float*)d_in[13];
    const float* lng  = (const float*)d_in[14];
    const float* lnb  = (const float*)d_in[15];
    float* out = (float*)d_out;

    char* p = (char*)d_ws;
    auto take = [&](size_t n) { char* r = p; p += (n + 255) & ~(size_t)255; return r; };
    short* xb   = (short*)take((size_t)T_TOK * DDIM * 2);
    short* w1t  = (short*)take((size_t)NEXP * FDIM * DDIM * 2);
    short* w2t  = (short*)take((size_t)NEXP * DDIM * FDIM * 2);
    short* sw1t = (short*)take((size_t)F2DIM * DDIM * 2);
    short* sw2t = (short*)take((size_t)DDIM * F2DIM * 2);
    short* hbuf = (short*)take((size_t)2 * T_TOK * FDIM * 2);
    short* hs   = (short*)take((size_t)T_TOK * F2DIM * 2);
    unsigned short* ybuf = (unsigned short*)take((size_t)2 * T_TOK * DDIM * 2);
    unsigned short* ysh  = (unsigned short*)take((size_t)T_TOK * DDIM * 2);
    int* eid    = (int*)take((size_t)T_TOK * 2 * 4);
    float* ewt  = (float*)take((size_t)T_TOK * 2 * 4);
    int* rowtok = (int*)take((size_t)2 * T_TOK * 4);
    float* roww = (float*)take((size_t)2 * T_TOK * 4);
    int* cnt    = (int*)take(64);
    int* offs   = (int*)take(64);
    int* cursor = (int*)take(64);

    hipMemsetAsync(cnt, 0, NEXP * sizeof(int), stream);
    k_router<<<T_TOK / 4, 256, 0, stream>>>(x, rw, rb, eid, ewt, cnt);
    k_scan<<<1, 64, 0, stream>>>(cnt, offs, cursor);
    k_scatter<<<T_TOK / 256, 256, 0, stream>>>(eid, ewt, cursor, rowtok, roww);

    k_cvt<<<2048, 256, 0, stream>>>(x, (unsigned short*)xb, (long long)T_TOK * DDIM / 4);
    k_tp<<<dim3(FDIM / 32, DDIM / 32, NEXP), 256, 0, stream>>>(w1, (unsigned short*)w1t, DDIM, FDIM);
    k_tp<<<dim3(DDIM / 32, FDIM / 32, NEXP), 256, 0, stream>>>(w2, (unsigned short*)w2t, FDIM, DDIM);
    k_tp<<<dim3(F2DIM / 32, DDIM / 32, 1), 256, 0, stream>>>(sw1, (unsigned short*)sw1t, DDIM, F2DIM);
    k_tp<<<dim3(DDIM / 32, F2DIM / 32, 1), 256, 0, stream>>>(sw2, (unsigned short*)sw2t, F2DIM, DDIM);

    // fc1 moe: [rows,1024] @ w1t[e][4096,1024]^T -> hbuf [rows,4096]
    k_gemm<0><<<dim3(FDIM / 128, T_TOK / 128, NEXP), 256, 0, stream>>>(
        xb, w1t, b1, gate, (unsigned short*)hbuf, cnt, offs, rowtok, roww, swt,
        DDIM, FDIM, (long long)FDIM * DDIM, FDIM);
    // fc2 moe: hbuf [rows,4096] @ w2t[e][1024,4096]^T -> ybuf slots
    k_gemm<1><<<dim3(DDIM / 128, T_TOK / 128, NEXP), 256, 0, stream>>>(
        hbuf, w2t, b2, gate, ybuf, cnt, offs, rowtok, roww, swt,
        FDIM, DDIM, (long long)DDIM * FDIM, DDIM);
    // shared fc1: xb [8192,1024] @ sw1t[2048,1024]^T -> hs
    k_gemm<2><<<dim3(F2DIM / 128, T_TOK / 128, 1), 256, 0, stream>>>(
        xb, sw1t, sb1, sgate, (unsigned short*)hs, cnt, offs, rowtok, roww, swt,
        DDIM, F2DIM, 0, 0);
    // shared fc2: hs [8192,2048] @ sw2t[1024,2048]^T -> ysh
    k_gemm<3><<<dim3(DDIM / 128, T_TOK / 128, 1), 256, 0, stream>>>(
        hs, sw2t, sb2, sgate, ysh, cnt, offs, rowtok, roww, swt,
        F2DIM, DDIM, 0, 0);

    k_ln<<<T_TOK / 4, 256, 0, stream>>>(ybuf, ybuf + (size_t)T_TOK * DDIM, ysh, lng, lnb, out);
}